// Round 6
// baseline (224.257 us; speedup 1.0000x reference)
//
#include <hip/hip_runtime.h>

typedef __attribute__((ext_vector_type(16))) float f32x16;
typedef unsigned long long u64;

// ---------------------------------------------------------------------------
// Quantize y (f32, 128 x N row-major) -> fp8 e4m3fn in B-fragment-major pack:
//   bp u64 index = (n/32)*512 + kk*64 + lane,  lane = h*32 + c
//   holds y[kk*16 + h*8 .. +8][n32*32 + c]
// Small (2.5 MB moved); runs before the fused GEMM.
// ---------------------------------------------------------------------------
__global__ void quant_y_pack(const float* __restrict__ y,
                             const float* __restrict__ scale,
                             u64* __restrict__ bp, int N, int total) {
    int t = blockIdx.x * blockDim.x + threadIdx.x;   // total = N*16
    if (t >= total) return;
    float s = scale[0];
    int lane = t & 63;
    int kk   = (t >> 6) & 7;
    int n32  = t >> 9;
    int c = lane & 31, h = lane >> 5;
    const float* src = y + (size_t)(kk * 16 + h * 8) * N + n32 * 32 + c;
    float v[8];
#pragma unroll
    for (int j = 0; j < 8; ++j) v[j] = src[(size_t)j * N] * s;
    int lo = 0, hi = 0;
    lo = __builtin_amdgcn_cvt_pk_fp8_f32(v[0], v[1], lo, false);
    lo = __builtin_amdgcn_cvt_pk_fp8_f32(v[2], v[3], lo, true);
    hi = __builtin_amdgcn_cvt_pk_fp8_f32(v[4], v[5], hi, false);
    hi = __builtin_amdgcn_cvt_pk_fp8_f32(v[6], v[7], hi, true);
    bp[t] = ((u64)(unsigned int)hi << 32) | (unsigned int)lo;
}

// ---------------------------------------------------------------------------
// Fused x-quant + GEMM: [M x 128]f32 -> fp8 in-register, @ [128 x N]fp8 -> f32.
// Block = 32 rows x 512 cols, 256 threads = 4 waves side by side, each wave a
// 32x128 strip = 4 n-frags of mfma_f32_32x32x16_fp8_fp8. K=128 in registers.
//
// Round-6 change: A-fragments are built in the prologue from the f32 x rows
// directly (lane h*32+r loads x[m0+r][kk*16+h*8..+8], scales, cvt_pk -> u64),
// eliminating the ap HBM round-trip (8.4 MB write + 8.4 MB cross-XCD read)
// and one kernel-serialization point. The 32x128 f32 panel (16 KB) is shared
// by the 8 same-band blocks, which the XCD swizzle co-locates -> 1x HBM read.
//
// Proven-and-kept: 256 threads (round-4 spill lesson: 1024 thr forced VGPR=64
// + 6.5 GB scratch thrash); NONTEMPORAL output stores (round-3: write stream
// must not evict fp8/bp panels from L2, -23%); bx-fast bijective XCD swizzle
// + contiguous 2 KB row segments per block (round-5: +4%).
//   A/B frag: lane = h*32 + r holds 8 fp8 at [r][kk*16 + h*8..+8]
//   C/D: col = lane&31, row = (reg&3) + 8*(reg>>2) + 4*(lane>>5)  [m74/m101]
// ---------------------------------------------------------------------------
__global__ __launch_bounds__(256) void gemm_fp8_kernel(
    const float* __restrict__ x, const u64* __restrict__ bp,
    const float* __restrict__ xs, const float* __restrict__ ys,
    float* __restrict__ out, int M, int N, int nb) {
    int nwg = gridDim.x;             // multiple of 8
    int cpx = nwg >> 3;
    int bid = blockIdx.x;
    int swz = (bid & 7) * cpx + (bid >> 3);   // bijective XCD swizzle
    int bx  = swz % nb;                        // bx-fast: linear write sweep
    int by  = swz / nb;

    int wid  = threadIdx.x >> 6;     // 0..3
    int lane = threadIdx.x & 63;
    int r    = lane & 31;
    int h    = lane >> 5;
    int m0   = by * 32;
    int n0   = bx * 512 + wid * 128;

    float s   = xs[0];
    float inv = 1.0f / (xs[0] * ys[0]);

    // ---- prologue: build A-fragments from f32 x rows (in-register quant) ----
    const float* xsrc = x + (size_t)(m0 + r) * 128 + h * 8;   // + kk*16
    u64 afr[8];
#pragma unroll
    for (int kk = 0; kk < 8; ++kk) {
        float4 a = *reinterpret_cast<const float4*>(xsrc + kk * 16);
        float4 b = *reinterpret_cast<const float4*>(xsrc + kk * 16 + 4);
        int lo = 0, hi = 0;
        lo = __builtin_amdgcn_cvt_pk_fp8_f32(a.x * s, a.y * s, lo, false);
        lo = __builtin_amdgcn_cvt_pk_fp8_f32(a.z * s, a.w * s, lo, true);
        hi = __builtin_amdgcn_cvt_pk_fp8_f32(b.x * s, b.y * s, hi, false);
        hi = __builtin_amdgcn_cvt_pk_fp8_f32(b.z * s, b.w * s, hi, true);
        afr[kk] = ((u64)(unsigned int)hi << 32) | (unsigned int)lo;
    }

    const u64* bbase = bp + (size_t)(n0 >> 5) * 512 + lane;   // + nf*512 + kk*64

    f32x16 acc[4] = {};

#pragma unroll
    for (int kk = 0; kk < 8; ++kk) {
        long a = (long)afr[kk];
#pragma unroll
        for (int nf = 0; nf < 4; ++nf) {
            long b = (long)bbase[(size_t)nf * 512 + kk * 64];
            acc[nf] = __builtin_amdgcn_mfma_f32_32x32x16_fp8_fp8(a, b, acc[nf], 0, 0, 0);
        }
    }

    int col = lane & 31;
    int h4  = h * 4;
    // rg-outer / nf-inner: per rg the wave writes 4 adjacent 128B lines of one
    // row (512B burst); 4 waves cover a contiguous 2KB row segment.
#pragma unroll
    for (int rg = 0; rg < 16; ++rg) {
        int row = (rg & 3) + 8 * (rg >> 2) + h4;
        float* o = out + (size_t)(m0 + row) * N + n0 + col;
#pragma unroll
        for (int nf = 0; nf < 4; ++nf)
            __builtin_nontemporal_store(acc[nf][rg] * inv, o + nf * 32);
    }
}

extern "C" void kernel_launch(void* const* d_in, const int* in_sizes, int n_in,
                              void* d_out, int out_size, void* d_ws, size_t ws_size,
                              hipStream_t stream) {
    const float* x  = (const float*)d_in[0];   // (B,S,K) f32
    const float* y  = (const float*)d_in[1];   // (K,N)   f32
    const float* xs = (const float*)d_in[2];   // scalar
    const float* ys = (const float*)d_in[3];   // scalar
    float* out = (float*)d_out;

    const int K = 128;
    int M = in_sizes[0] / K;   // 65536
    int N = in_sizes[1] / K;   // 4096

    u64* bp = (u64*)d_ws;                      // K*N bytes

    int ty = N * (K / 8);                      // 65536
    quant_y_pack<<<(ty + 255) / 256, 256, 0, stream>>>(y, ys, bp, N, ty);

    int nb = N / 512;                          // 8
    int grid = (M / 32) * nb;                  // 16384, %8 == 0
    gemm_fp8_kernel<<<grid, 256, 0, stream>>>(x, bp, xs, ys, out, M, N, nb);
}

// Round 7
// 196.929 us; speedup vs baseline: 1.1388x; 1.1388x over previous
//
#include <hip/hip_runtime.h>

typedef __attribute__((ext_vector_type(16))) float f32x16;
typedef __attribute__((ext_vector_type(4)))  float f32x4v;
typedef unsigned long long u64;

// ---------------------------------------------------------------------------
// Fused quantize of x and y -> fp8 e4m3fn in fragment-major packs.
//   x: (M x 128 row-major) -> ap: u64 idx = (m/32)*512 + kk*64 + lane,
//      lane = h*32 + r holds x[m32*32+r][kk*16+h*8 .. +8]
//   y: (128 x N row-major) -> bp: u64 idx = (n/32)*512 + kk*64 + lane,
//      lane = h*32 + c holds y[kk*16+h*8 .. +8][n32*32+c]
// NONTEMPORAL loads: x/y f32 are read exactly once — don't let 35.5 MB of
// dead data evict the just-written ap/bp packs from L2 (round-7 delta).
// ---------------------------------------------------------------------------
__global__ void quant_pack_all(const float* __restrict__ x,
                               const float* __restrict__ y,
                               const float* __restrict__ xs,
                               const float* __restrict__ ys,
                               u64* __restrict__ ap, u64* __restrict__ bp,
                               int N, int tx, int total) {
    int t = blockIdx.x * blockDim.x + threadIdx.x;
    if (t >= total) return;
    if (t < tx) {
        float s = xs[0];
        int lane = t & 63;
        int kk   = (t >> 6) & 7;
        int m32  = t >> 9;
        int r = lane & 31, h = lane >> 5;
        const float* src = x + ((size_t)(m32 * 32 + r)) * 128 + kk * 16 + h * 8;
        f32x4v a = __builtin_nontemporal_load(reinterpret_cast<const f32x4v*>(src));
        f32x4v b = __builtin_nontemporal_load(reinterpret_cast<const f32x4v*>(src + 4));
        int lo = 0, hi = 0;
        lo = __builtin_amdgcn_cvt_pk_fp8_f32(a.x * s, a.y * s, lo, false);
        lo = __builtin_amdgcn_cvt_pk_fp8_f32(a.z * s, a.w * s, lo, true);
        hi = __builtin_amdgcn_cvt_pk_fp8_f32(b.x * s, b.y * s, hi, false);
        hi = __builtin_amdgcn_cvt_pk_fp8_f32(b.z * s, b.w * s, hi, true);
        ap[t] = ((u64)(unsigned int)hi << 32) | (unsigned int)lo;
    } else {
        t -= tx;
        float s = ys[0];
        int lane = t & 63;
        int kk   = (t >> 6) & 7;
        int n32  = t >> 9;
        int c = lane & 31, h = lane >> 5;
        const float* src = y + (size_t)(kk * 16 + h * 8) * N + n32 * 32 + c;
        float v[8];
#pragma unroll
        for (int j = 0; j < 8; ++j)
            v[j] = __builtin_nontemporal_load(src + (size_t)j * N) * s;
        int lo = 0, hi = 0;
        lo = __builtin_amdgcn_cvt_pk_fp8_f32(v[0], v[1], lo, false);
        lo = __builtin_amdgcn_cvt_pk_fp8_f32(v[2], v[3], lo, true);
        hi = __builtin_amdgcn_cvt_pk_fp8_f32(v[4], v[5], hi, false);
        hi = __builtin_amdgcn_cvt_pk_fp8_f32(v[6], v[7], hi, true);
        bp[t] = ((u64)(unsigned int)hi << 32) | (unsigned int)lo;
    }
}

// ---------------------------------------------------------------------------
// GEMM: [M x 128]fp8 @ [128 x N]fp8 -> f32 * inv.  (round-5 proven structure;
// round-6's in-GEMM x-quant REGRESSED — per-lane 16B gathers across 32 rows
// are 32-way line-split; packing wants a dedicated coalesced pass.)
// Block = 32 rows x 512 cols, 256 threads = 4 waves side by side, each wave a
// 32x128 strip = 4 n-frags of mfma_f32_32x32x16_fp8_fp8. K=128 in registers,
// no LDS. 256 threads only (round-4: 1024-thr forced VGPR=64 + 6.5 GB spill
// thrash). NONTEMPORAL stores (round-3, -23%: write stream must not evict the
// fp8 panels from L2). bx-fast bijective XCD swizzle + contiguous 2 KB row
// segments per block (round-5, -4%).
//   A/B frag: lane = h*32 + r holds 8 fp8 at [r][kk*16 + h*8..+8]
//   C/D: col = lane&31, row = (reg&3) + 8*(reg>>2) + 4*(lane>>5)  [m74/m101]
// ---------------------------------------------------------------------------
__global__ __launch_bounds__(256) void gemm_fp8_kernel(
    const u64* __restrict__ ap, const u64* __restrict__ bp,
    const float* __restrict__ xs, const float* __restrict__ ys,
    float* __restrict__ out, int M, int N, int nb) {
    int nwg = gridDim.x;             // multiple of 8
    int cpx = nwg >> 3;
    int bid = blockIdx.x;
    int swz = (bid & 7) * cpx + (bid >> 3);   // bijective XCD swizzle
    int bx  = swz % nb;                        // bx-fast: linear write sweep
    int by  = swz / nb;

    int wid  = threadIdx.x >> 6;     // 0..3
    int lane = threadIdx.x & 63;
    int m0   = by * 32;
    int n0   = bx * 512 + wid * 128;

    float inv = 1.0f / (xs[0] * ys[0]);

    const u64* abase = ap + (size_t)(m0 >> 5) * 512 + lane;   // + kk*64
    const u64* bbase = bp + (size_t)(n0 >> 5) * 512 + lane;   // + nf*512 + kk*64

    f32x16 acc[4] = {};

#pragma unroll
    for (int kk = 0; kk < 8; ++kk) {
        long a = (long)abase[kk * 64];
#pragma unroll
        for (int nf = 0; nf < 4; ++nf) {
            long b = (long)bbase[(size_t)nf * 512 + kk * 64];
            acc[nf] = __builtin_amdgcn_mfma_f32_32x32x16_fp8_fp8(a, b, acc[nf], 0, 0, 0);
        }
    }

    int col = lane & 31;
    int h4  = (lane >> 5) * 4;
    // rg-outer / nf-inner: per rg the wave writes 4 adjacent 128B lines of one
    // row (512B burst); 4 waves cover a contiguous 2KB row segment.
#pragma unroll
    for (int rg = 0; rg < 16; ++rg) {
        int row = (rg & 3) + 8 * (rg >> 2) + h4;
        float* o = out + (size_t)(m0 + row) * N + n0 + col;
#pragma unroll
        for (int nf = 0; nf < 4; ++nf)
            __builtin_nontemporal_store(acc[nf][rg] * inv, o + nf * 32);
    }
}

extern "C" void kernel_launch(void* const* d_in, const int* in_sizes, int n_in,
                              void* d_out, int out_size, void* d_ws, size_t ws_size,
                              hipStream_t stream) {
    const float* x  = (const float*)d_in[0];   // (B,S,K) f32
    const float* y  = (const float*)d_in[1];   // (K,N)   f32
    const float* xs = (const float*)d_in[2];   // scalar
    const float* ys = (const float*)d_in[3];   // scalar
    float* out = (float*)d_out;

    const int K = 128;
    int M = in_sizes[0] / K;   // 65536
    int N = in_sizes[1] / K;   // 4096

    u64* ap = (u64*)d_ws;                      // M*K bytes
    u64* bp = ap + (size_t)M * K / 8;          // K*N bytes

    int tx = M * (K / 8);                      // 1048576 (multiple of 256)
    int ty = N * (K / 8);                      // 65536
    int total = tx + ty;
    quant_pack_all<<<(total + 255) / 256, 256, 0, stream>>>(x, y, xs, ys, ap, bp,
                                                            N, tx, total);

    int nb = N / 512;                          // 8
    int grid = (M / 32) * nb;                  // 16384, %8 == 0
    gemm_fp8_kernel<<<grid, 256, 0, stream>>>(ap, bp, xs, ys, out, M, N, nb);
}

// Round 8
// 189.480 us; speedup vs baseline: 1.1835x; 1.0393x over previous
//
#include <hip/hip_runtime.h>

typedef __attribute__((ext_vector_type(16))) float f32x16;
typedef unsigned long long u64;

// ---------------------------------------------------------------------------
// Fused quantize of x and y -> fp8 e4m3fn in fragment-major packs.
//   x: (M x 128 row-major) -> ap: u64 idx = (m/32)*512 + kk*64 + h*32 + r,
//      holding x[m32*32+r][kk*16+h*8 .. +8]
//   y: (128 x N row-major) -> bp: u64 idx = (n/32)*512 + kk*64 + h*32 + c,
//      holding y[kk*16+h*8 .. +8][n32*32+c]
// Round-8 x-pack fix: thread t reads the 8 LINEARLY CONSECUTIVE floats
// x[8t..8t+8) -> wave loads are contiguous 2 KB (the old r-major mapping was
// a 32-way 512B-stride line-split gather per load instr). The fragment
// scatter moves to the store side (8B granule within a 4KB block), which is
// fire-and-forget and merged by L2. Same ap layout, same values.
// Round-7 lesson: NO nt on these loads — nt defeated same-line reuse between
// the paired 16B loads and re-fetched from HBM (+7.6 us).
// ---------------------------------------------------------------------------
__global__ void quant_pack_all(const float* __restrict__ x,
                               const float* __restrict__ y,
                               const float* __restrict__ xs,
                               const float* __restrict__ ys,
                               u64* __restrict__ ap, u64* __restrict__ bp,
                               int N, int tx, int total) {
    int t = blockIdx.x * blockDim.x + threadIdx.x;
    if (t >= total) return;
    if (t < tx) {
        float s = xs[0];
        const float* src = x + (size_t)t * 8;      // coalesced: 2 KB per wave
        float4 a = *reinterpret_cast<const float4*>(src);
        float4 b = *reinterpret_cast<const float4*>(src + 4);
        int r   = (t >> 4) & 31;                   // row % 32
        int m32 = t >> 9;                          // row / 32
        int kk  = (t >> 1) & 7;                    // k-chunk
        int h   = t & 1;                           // k-half
        int lo = 0, hi = 0;
        lo = __builtin_amdgcn_cvt_pk_fp8_f32(a.x * s, a.y * s, lo, false);
        lo = __builtin_amdgcn_cvt_pk_fp8_f32(a.z * s, a.w * s, lo, true);
        hi = __builtin_amdgcn_cvt_pk_fp8_f32(b.x * s, b.y * s, hi, false);
        hi = __builtin_amdgcn_cvt_pk_fp8_f32(b.z * s, b.w * s, hi, true);
        ap[(size_t)m32 * 512 + kk * 64 + h * 32 + r] =
            ((u64)(unsigned int)hi << 32) | (unsigned int)lo;
    } else {
        t -= tx;
        float s = ys[0];
        int lane = t & 63;
        int kk   = (t >> 6) & 7;
        int n32  = t >> 9;
        int c = lane & 31, h = lane >> 5;
        const float* src = y + (size_t)(kk * 16 + h * 8) * N + n32 * 32 + c;
        float v[8];
#pragma unroll
        for (int j = 0; j < 8; ++j) v[j] = src[(size_t)j * N] * s;
        int lo = 0, hi = 0;
        lo = __builtin_amdgcn_cvt_pk_fp8_f32(v[0], v[1], lo, false);
        lo = __builtin_amdgcn_cvt_pk_fp8_f32(v[2], v[3], lo, true);
        hi = __builtin_amdgcn_cvt_pk_fp8_f32(v[4], v[5], hi, false);
        hi = __builtin_amdgcn_cvt_pk_fp8_f32(v[6], v[7], hi, true);
        bp[t] = ((u64)(unsigned int)hi << 32) | (unsigned int)lo;
    }
}

// ---------------------------------------------------------------------------
// GEMM: [M x 128]fp8 @ [128 x N]fp8 -> f32 * inv.  (round-5 proven structure,
// byte-identical — best measured 189.3 us.)
// Block = 32 rows x 512 cols, 256 threads = 4 waves side by side, each wave a
// 32x128 strip = 4 n-frags of mfma_f32_32x32x16_fp8_fp8. K=128 in registers,
// no LDS. 256 threads only (round-4: 1024-thr forced VGPR=64 + 6.5 GB spill
// thrash). NONTEMPORAL stores (round-3, -23%: write stream must not evict the
// fp8 panels from L2). bx-fast bijective XCD swizzle + contiguous 2 KB row
// segments per block (round-5, -4%).
//   A/B frag: lane = h*32 + r holds 8 fp8 at [r][kk*16 + h*8..+8]
//   C/D: col = lane&31, row = (reg&3) + 8*(reg>>2) + 4*(lane>>5)  [m74/m101]
// ---------------------------------------------------------------------------
__global__ __launch_bounds__(256) void gemm_fp8_kernel(
    const u64* __restrict__ ap, const u64* __restrict__ bp,
    const float* __restrict__ xs, const float* __restrict__ ys,
    float* __restrict__ out, int M, int N, int nb) {
    int nwg = gridDim.x;             // multiple of 8
    int cpx = nwg >> 3;
    int bid = blockIdx.x;
    int swz = (bid & 7) * cpx + (bid >> 3);   // bijective XCD swizzle
    int bx  = swz % nb;                        // bx-fast: linear write sweep
    int by  = swz / nb;

    int wid  = threadIdx.x >> 6;     // 0..3
    int lane = threadIdx.x & 63;
    int m0   = by * 32;
    int n0   = bx * 512 + wid * 128;

    float inv = 1.0f / (xs[0] * ys[0]);

    const u64* abase = ap + (size_t)(m0 >> 5) * 512 + lane;   // + kk*64
    const u64* bbase = bp + (size_t)(n0 >> 5) * 512 + lane;   // + nf*512 + kk*64

    f32x16 acc[4] = {};

#pragma unroll
    for (int kk = 0; kk < 8; ++kk) {
        long a = (long)abase[kk * 64];
#pragma unroll
        for (int nf = 0; nf < 4; ++nf) {
            long b = (long)bbase[(size_t)nf * 512 + kk * 64];
            acc[nf] = __builtin_amdgcn_mfma_f32_32x32x16_fp8_fp8(a, b, acc[nf], 0, 0, 0);
        }
    }

    int col = lane & 31;
    int h4  = (lane >> 5) * 4;
    // rg-outer / nf-inner: per rg the wave writes 4 adjacent 128B lines of one
    // row (512B burst); 4 waves cover a contiguous 2KB row segment.
#pragma unroll
    for (int rg = 0; rg < 16; ++rg) {
        int row = (rg & 3) + 8 * (rg >> 2) + h4;
        float* o = out + (size_t)(m0 + row) * N + n0 + col;
#pragma unroll
        for (int nf = 0; nf < 4; ++nf)
            __builtin_nontemporal_store(acc[nf][rg] * inv, o + nf * 32);
    }
}

extern "C" void kernel_launch(void* const* d_in, const int* in_sizes, int n_in,
                              void* d_out, int out_size, void* d_ws, size_t ws_size,
                              hipStream_t stream) {
    const float* x  = (const float*)d_in[0];   // (B,S,K) f32
    const float* y  = (const float*)d_in[1];   // (K,N)   f32
    const float* xs = (const float*)d_in[2];   // scalar
    const float* ys = (const float*)d_in[3];   // scalar
    float* out = (float*)d_out;

    const int K = 128;
    int M = in_sizes[0] / K;   // 65536
    int N = in_sizes[1] / K;   // 4096

    u64* ap = (u64*)d_ws;                      // M*K bytes
    u64* bp = ap + (size_t)M * K / 8;          // K*N bytes

    int tx = M * (K / 8);                      // 1048576 (multiple of 256)
    int ty = N * (K / 8);                      // 65536
    int total = tx + ty;
    quant_pack_all<<<(total + 255) / 256, 256, 0, stream>>>(x, y, xs, ys, ap, bp,
                                                            N, tx, total);

    int nb = N / 512;                          // 8
    int grid = (M / 32) * nb;                  // 16384, %8 == 0
    gemm_fp8_kernel<<<grid, 256, 0, stream>>>(ap, bp, xs, ys, out, M, N, nb);
}

// Round 10
// 180.230 us; speedup vs baseline: 1.2443x; 1.0513x over previous
//
#include <hip/hip_runtime.h>

typedef __attribute__((ext_vector_type(16))) float f32x16;
typedef unsigned long long u64;

// ---------------------------------------------------------------------------
// Quantize y (f32, 128 x N row-major) -> fp8 e4m3fn in B-fragment-major pack:
//   bp u64 idx = (n/32)*512 + kk*64 + h*32 + c, holding y[kk*16+h*8..+8][n32*32+c]
// x is quantized inside the GEMM; this kernel moves ~2.5 MB.
// ---------------------------------------------------------------------------
__global__ void quant_y_pack(const float* __restrict__ y,
                             const float* __restrict__ scale,
                             u64* __restrict__ bp, int N, int total) {
    int t = blockIdx.x * blockDim.x + threadIdx.x;   // total = N*16
    if (t >= total) return;
    float s = scale[0];
    int lane = t & 63;
    int kk   = (t >> 6) & 7;
    int n32  = t >> 9;
    int c = lane & 31, h = lane >> 5;
    const float* src = y + (size_t)(kk * 16 + h * 8) * N + n32 * 32 + c;
    float v[8];
#pragma unroll
    for (int j = 0; j < 8; ++j) v[j] = src[(size_t)j * N] * s;
    int lo = 0, hi = 0;
    lo = __builtin_amdgcn_cvt_pk_fp8_f32(v[0], v[1], lo, false);
    lo = __builtin_amdgcn_cvt_pk_fp8_f32(v[2], v[3], lo, true);
    hi = __builtin_amdgcn_cvt_pk_fp8_f32(v[4], v[5], hi, false);
    hi = __builtin_amdgcn_cvt_pk_fp8_f32(v[6], v[7], hi, true);
    bp[t] = ((u64)(unsigned int)hi << 32) | (unsigned int)lo;
}

// ---------------------------------------------------------------------------
// Fused x-quant + GEMM: [M x 128]f32 @ [128 x N]fp8 -> f32 * inv.
// Block = 32 rows x 512 cols, 256 threads = 4 waves side by side, each wave a
// 32x128 strip = 4 n-frags of mfma_f32_32x32x16_fp8_fp8. K=128 in registers.
//
// Round-10 fix of round-9 crash: staging loop stride was it*4096 (4x LDS
// overrun -> OOB LDS writes, core dump); panel is 4096 floats, 1024 per
// iteration -> it*1024.
//
// x-quant fused via LDS: 4x coalesced dwordx4 loads per thread, quantize
// float4->u32 (2x cvt_pk) BEFORE LDS, write 4KB fp8 panel with XOR swizzle
// byte ^= (row&15)<<3 (bijective per row; 2-way banks = free, G4/m136),
// barrier, ds_read_b64 per A-fragment. Eliminates the ap HBM round-trip
// (17 MB) + the big quant launch. The 16KB f32 panel is shared by the 8
// same-band blocks, co-located on one XCD by the swizzle -> L2 hits.
//
// Proven-and-kept: 256 threads (round-4: 1024-thr forced VGPR=64 + spill
// thrash); NONTEMPORAL stores (round-3, -23%); bx-fast bijective XCD swizzle
// + contiguous 2KB row segments (round-5, -4%); no nt on one-touch loads that
// share cache lines (round-7, +7.6us lesson).
//   B frag: lane = h*32 + c holds 8 fp8 at [kk*16+h*8..+8][c]
//   C/D: col = lane&31, row = (reg&3) + 8*(reg>>2) + 4*(lane>>5)  [m74/m101]
// ---------------------------------------------------------------------------
__global__ __launch_bounds__(256) void gemm_fp8_fused(
    const float* __restrict__ x, const u64* __restrict__ bp,
    const float* __restrict__ xs, const float* __restrict__ ys,
    float* __restrict__ out, int M, int N, int nb) {
    __shared__ unsigned int xpan[1024];   // 4 KB fp8 panel, swizzled

    int nwg = gridDim.x;             // multiple of 8
    int cpx = nwg >> 3;
    int bid = blockIdx.x;
    int swz = (bid & 7) * cpx + (bid >> 3);   // bijective XCD swizzle
    int bx  = swz % nb;                        // bx-fast: linear write sweep
    int by  = swz / nb;

    int tid  = threadIdx.x;
    int wid  = tid >> 6;             // 0..3
    int lane = tid & 63;
    int m0   = by * 32;
    int n0   = bx * 512 + wid * 128;

    float s   = xs[0];
    float inv = 1.0f / (xs[0] * ys[0]);

    // ---- stage + quantize the 32x128 f32 x-panel into LDS (fp8) ----
    const float* xp = x + (size_t)m0 * 128;
#pragma unroll
    for (int it = 0; it < 4; ++it) {
        int f = it * 1024 + tid * 4;             // f32 index within panel [0,4096)
        float4 v = *reinterpret_cast<const float4*>(xp + f);
        unsigned int w = 0;
        w = __builtin_amdgcn_cvt_pk_fp8_f32(v.x * s, v.y * s, w, false);
        w = __builtin_amdgcn_cvt_pk_fp8_f32(v.z * s, v.w * s, w, true);
        int row = f >> 7;
        int col = f & 127;                        // byte col within row
        int sb  = (row << 7) + (col ^ ((row & 15) << 3));   // swizzled byte
        xpan[sb >> 2] = w;
    }
    __syncthreads();

    // ---- read A-fragments from LDS: lane h*32+r wants x[r][kk*16+h*8..+8] ----
    int r = lane & 31;
    int h = lane >> 5;
    const char* xb = reinterpret_cast<const char*>(xpan);
    u64 afr[8];
#pragma unroll
    for (int kk = 0; kk < 8; ++kk) {
        int b = (r << 7) + ((kk * 16 + h * 8) ^ ((r & 15) << 3));
        afr[kk] = *reinterpret_cast<const u64*>(xb + b);
    }

    const u64* bbase = bp + (size_t)(n0 >> 5) * 512 + lane;   // + nf*512 + kk*64

    f32x16 acc[4] = {};

#pragma unroll
    for (int kk = 0; kk < 8; ++kk) {
        long a = (long)afr[kk];
#pragma unroll
        for (int nf = 0; nf < 4; ++nf) {
            long b = (long)bbase[(size_t)nf * 512 + kk * 64];
            acc[nf] = __builtin_amdgcn_mfma_f32_32x32x16_fp8_fp8(a, b, acc[nf], 0, 0, 0);
        }
    }

    int col = lane & 31;
    int h4  = h * 4;
    // rg-outer / nf-inner: per rg the wave writes 4 adjacent 128B lines of one
    // row (512B burst); 4 waves cover a contiguous 2KB row segment.
#pragma unroll
    for (int rg = 0; rg < 16; ++rg) {
        int row = (rg & 3) + 8 * (rg >> 2) + h4;
        float* o = out + (size_t)(m0 + row) * N + n0 + col;
#pragma unroll
        for (int nf = 0; nf < 4; ++nf)
            __builtin_nontemporal_store(acc[nf][rg] * inv, o + nf * 32);
    }
}

extern "C" void kernel_launch(void* const* d_in, const int* in_sizes, int n_in,
                              void* d_out, int out_size, void* d_ws, size_t ws_size,
                              hipStream_t stream) {
    const float* x  = (const float*)d_in[0];   // (B,S,K) f32
    const float* y  = (const float*)d_in[1];   // (K,N)   f32
    const float* xs = (const float*)d_in[2];   // scalar
    const float* ys = (const float*)d_in[3];   // scalar
    float* out = (float*)d_out;

    const int K = 128;
    int M = in_sizes[0] / K;   // 65536
    int N = in_sizes[1] / K;   // 4096

    u64* bp = (u64*)d_ws;                      // K*N bytes

    int ty = N * (K / 8);                      // 65536
    quant_y_pack<<<(ty + 255) / 256, 256, 0, stream>>>(y, ys, bp, N, ty);

    int nb = N / 512;                          // 8
    int grid = (M / 32) * nb;                  // 16384, %8 == 0
    gemm_fp8_fused<<<grid, 256, 0, stream>>>(x, bp, xs, ys, out, M, N, nb);
}